// Round 1
// baseline (651.693 us; speedup 1.0000x reference)
//
#include <hip/hip_runtime.h>

// MultiMiniInterv: out = base; for 4 fixed 16-wide channel regions g at
// STARTS={0,752,184,568}: out[:, s:s+16] += ((Ws_g - Wp_g) x + (bs_g - bp_g)) @ Wp_g
// base: [1, B=131072, 768] f32; Wp/Ws: [4, 8, 16]; bp/bs: [4, 8].
// Memory-bound copy (805 MB traffic) with tiny fused per-row correction.

constexpr int ROWS_PER_BLOCK = 8;
constexpr int F4_PER_ROW = 192;   // 768 / 4

__global__ __launch_bounds__(192) void multi_mini_interv_kernel(
    const float* __restrict__ base,
    const float* __restrict__ Wp,
    const float* __restrict__ bp,
    const float* __restrict__ Ws,
    const float* __restrict__ bs,
    float* __restrict__ out,
    int B)
{
    __shared__ float sWp[512];   // [g][r][e] = [4][8][16]
    __shared__ float sWd[512];   // Ws - Wp
    __shared__ float sbd[32];    // bs - bp, [4][8]

    const int tid = threadIdx.x;

    // Stage weights into LDS (tiny: 4.2 KB)
    for (int i = tid; i < 512; i += 192) {
        float wp = Wp[i];
        sWp[i] = wp;
        sWd[i] = Ws[i] - wp;
    }
    if (tid < 32) sbd[tid] = bs[tid] - bp[tid];
    __syncthreads();

    // Per-lane constant: which region (if any) does this float4 column touch?
    // f4 col ranges: g0: 0..3 (ch 0..15), g1: 188..191 (752..767),
    //                g2: 46..49 (184..199), g3: 142..145 (568..583)
    const int c = tid;   // float4 column in row, 0..191
    int g = -1, cbase = 0;
    if (c < 4)                    { g = 0; cbase = 0;   }
    else if (c >= 188)            { g = 1; cbase = 188; }
    else if (c >= 46 && c < 50)   { g = 2; cbase = 46;  }
    else if (c >= 142 && c < 146) { g = 3; cbase = 142; }
    const int off = (c - cbase) * 4;   // this lane's 4 channels within the 16-wide region

    const float4* __restrict__ base4 = (const float4*)base;
    float4* __restrict__ out4 = (float4*)out;

    const int row0 = blockIdx.x * ROWS_PER_BLOCK;
    #pragma unroll
    for (int rr = 0; rr < ROWS_PER_BLOCK; ++rr) {
        const int row = row0 + rr;
        if (row >= B) break;
        const float4* __restrict__ src = base4 + (size_t)row * F4_PER_ROW;
        float4 v = src[c];

        if (g >= 0) {
            // Load the full 16-wide region (redundant across the 4 lanes of
            // this region, but same cache lines -> L1 hits)
            float x[16];
            float4 x0 = src[cbase + 0];
            float4 x1 = src[cbase + 1];
            float4 x2 = src[cbase + 2];
            float4 x3 = src[cbase + 3];
            x[0]  = x0.x; x[1]  = x0.y; x[2]  = x0.z; x[3]  = x0.w;
            x[4]  = x1.x; x[5]  = x1.y; x[6]  = x1.z; x[7]  = x1.w;
            x[8]  = x2.x; x[9]  = x2.y; x[10] = x2.z; x[11] = x2.w;
            x[12] = x3.x; x[13] = x3.y; x[14] = x3.z; x[15] = x3.w;

            // t[r] = (Ws-Wp)_g[r,:] . x + (bs-bp)_g[r]
            float t[8];
            const float* wd = &sWd[g * 128];
            #pragma unroll
            for (int r = 0; r < 8; ++r) {
                float acc = sbd[g * 8 + r];
                #pragma unroll
                for (int e = 0; e < 16; ++e)
                    acc += x[e] * wd[r * 16 + e];
                t[r] = acc;
            }

            // delta[off..off+3] = sum_r t[r] * Wp_g[r, off..off+3]
            float d0 = 0.f, d1 = 0.f, d2 = 0.f, d3 = 0.f;
            const float* wp = &sWp[g * 128 + off];
            #pragma unroll
            for (int r = 0; r < 8; ++r) {
                const float tr = t[r];
                d0 += tr * wp[r * 16 + 0];
                d1 += tr * wp[r * 16 + 1];
                d2 += tr * wp[r * 16 + 2];
                d3 += tr * wp[r * 16 + 3];
            }
            v.x += d0; v.y += d1; v.z += d2; v.w += d3;
        }

        out4[(size_t)row * F4_PER_ROW + c] = v;
    }
}

extern "C" void kernel_launch(void* const* d_in, const int* in_sizes, int n_in,
                              void* d_out, int out_size, void* d_ws, size_t ws_size,
                              hipStream_t stream) {
    const float* base = (const float*)d_in[0];
    const float* Wp   = (const float*)d_in[1];
    const float* bp   = (const float*)d_in[2];
    const float* Ws   = (const float*)d_in[3];
    const float* bs   = (const float*)d_in[4];
    float* out = (float*)d_out;

    const int B = in_sizes[0] / 768;
    const int grid = (B + ROWS_PER_BLOCK - 1) / ROWS_PER_BLOCK;

    multi_mini_interv_kernel<<<grid, 192, 0, stream>>>(base, Wp, bp, Ws, bs, out, B);
}